// Round 2
// baseline (1256.588 us; speedup 1.0000x reference)
//
#include <hip/hip_runtime.h>
#include <hip/hip_bf16.h>

typedef unsigned short u16;
typedef unsigned long long u64;
typedef __bf16 bf16x8 __attribute__((ext_vector_type(8)));
typedef float f32x4 __attribute__((ext_vector_type(4)));

#define S_DIM 2048
#define B_DIM 32
#define H_DIM 1024
#define M_DIM (S_DIM * B_DIM)
#define BM 128
#define BKS 32
#define NKS (H_DIM / BKS)

__device__ __forceinline__ float fast_tanh(float x) {
  // tanh(x) = 1 - 2/(e^{2x}+1); e->inf => 1, e->0 => -1; no NaN
  float e = __expf(2.0f * x);
  return 1.0f - 2.0f * __builtin_amdgcn_rcpf(e + 1.0f);
}

__device__ __forceinline__ void gload_lds16(const void* g, void* l) {
  __builtin_amdgcn_global_load_lds(
      (const __attribute__((address_space(1))) unsigned int*)g,
      (__attribute__((address_space(3))) unsigned int*)l,
      16, 0, 0);
}

// Convert W_attn[:, H:2H] (f32, row stride 2H) -> W2 bf16 [H][H] row-major
__global__ void wconv_kernel(const float* __restrict__ W, u16* __restrict__ W2) {
  const int h = blockIdx.x;
  const int t = threadIdx.x; // 256 threads, 4 floats each
  float4 w4 = *(const float4*)(W + (size_t)h * (2 * H_DIM) + H_DIM + t * 4);
  union { u16 s[4]; uint2 v; } pk;
  pk.s[0] = __builtin_bit_cast(u16, (__bf16)w4.x);
  pk.s[1] = __builtin_bit_cast(u16, (__bf16)w4.y);
  pk.s[2] = __builtin_bit_cast(u16, (__bf16)w4.z);
  pk.s[3] = __builtin_bit_cast(u16, (__bf16)w4.w);
  *(uint2*)(W2 + (size_t)h * H_DIM + t * 4) = pk.v;
}

// u[b][h] = dot(hidden[b,:], W_attn[h, 0:H]) + b_attn[h]   (fp32)
__global__ void uprep_kernel(const float* __restrict__ hidden, const float* __restrict__ W,
                             const float* __restrict__ bias, float* __restrict__ u) {
  int t = blockIdx.x * 256 + threadIdx.x;   // 0..131071
  int h = t >> 7;
  int b = (t >> 2) & 31;
  int kq = t & 3;
  const float4* hv = (const float4*)(hidden + (size_t)b * H_DIM) + kq * 64;
  const float4* wv = (const float4*)(W + (size_t)h * (2 * H_DIM)) + kq * 64;
  float acc = 0.f;
  #pragma unroll 4
  for (int i = 0; i < 64; ++i) {
    float4 a = hv[i], w = wv[i];
    acc += a.x * w.x + a.y * w.y + a.z * w.z + a.w * w.w;
  }
  acc += __shfl_xor(acc, 1);
  acc += __shfl_xor(acc, 2);
  if (kq == 0) u[(size_t)b * H_DIM + h] = acc + bias[h];
}

// Fused GEMM + tanh + v-dot.
// Block: BM=128 rows x full N=1024. 1024 threads = 16 waves, wave tile 128m x 64n.
// A (enc f32->bf16) reg-staged into padded LDS; B (W2 bf16) via global_load_lds,
// both double-buffered, both-sides XOR swizzle on B (linear LDS dest constraint).
__launch_bounds__(1024)
__global__ void gemm_kernel(const float* __restrict__ enc, const u16* __restrict__ W2,
                            const float* __restrict__ u, const float* __restrict__ v,
                            float* __restrict__ scores) {
  __shared__ u16 A_s[2][BM][40];        // 40-elem rows: 80B, 16B-aligned chunks, ~2-way banks
  __shared__ u16 B_s[2][H_DIM * BKS];   // [col][4 chunks of 8 elems], chunk ^= (col>>1)&3
  __shared__ float red_s[16][BM];

  const int tid  = threadIdx.x;
  const int lane = tid & 63;
  const int wid  = tid >> 6;    // 0..15
  const int q    = lane >> 4;   // 0..3 (k-chunk)
  const int c16  = lane & 15;
  const int n0   = wid * 64;    // wave n-slice
  const int m0   = blockIdx.x * BM;

  // A staging coords: thread -> (row, 4-float chunk)
  const int ar  = tid >> 3;     // 0..127
  const int acf = tid & 7;      // 0..7
  const float* aptr = enc + (size_t)(m0 + ar) * H_DIM + acf * 4;

  f32x4 acc[8][4];
  #pragma unroll
  for (int mi = 0; mi < 8; ++mi)
    #pragma unroll
    for (int nf = 0; nf < 4; ++nf) {
      f32x4 z = {0.f, 0.f, 0.f, 0.f};
      acc[mi][nf] = z;
    }

  // ---- staging helpers (inlined) ----
  // B: 64KB = 1024 cols x 64B; thread does 4 gload_lds of 16B.
  //    LDS slot L16 = j*1024 + tid; h = L16>>2; cp = L16&3; src chunk = cp ^ ((h>>1)&3)
  #define STAGE_B(buf, ks)                                                     \
    {                                                                          \
      _Pragma("unroll")                                                        \
      for (int j = 0; j < 4; ++j) {                                            \
        const int L16 = j * 1024 + tid;                                        \
        const int h   = L16 >> 2;                                              \
        const int cp  = L16 & 3;                                               \
        const int c   = cp ^ ((h >> 1) & 3);                                   \
        gload_lds16(W2 + (size_t)h * H_DIM + (ks) * BKS + c * 8,               \
                    &B_s[buf][L16 * 8]);                                       \
      }                                                                        \
    }

  #define WRITE_A(buf, f4)                                                     \
    {                                                                          \
      union { u16 s[4]; u64 v; } pk;                                           \
      pk.s[0] = __builtin_bit_cast(u16, (__bf16)(f4).x);                       \
      pk.s[1] = __builtin_bit_cast(u16, (__bf16)(f4).y);                       \
      pk.s[2] = __builtin_bit_cast(u16, (__bf16)(f4).z);                       \
      pk.s[3] = __builtin_bit_cast(u16, (__bf16)(f4).w);                       \
      *(u64*)&A_s[buf][ar][acf * 4] = pk.v;                                    \
    }

  // ---- prologue ----
  STAGE_B(0, 0);
  {
    float4 a0 = *(const float4*)(aptr);
    WRITE_A(0, a0);
  }
  __syncthreads();

  // ---- K loop ----
  #pragma unroll 2
  for (int ks = 0; ks < NKS; ++ks) {
    const int cur = ks & 1;
    const int nxt = cur ^ 1;
    float4 av;
    if (ks + 1 < NKS) {
      STAGE_B(nxt, ks + 1);
      av = *(const float4*)(aptr + (ks + 1) * BKS);
    }
    bf16x8 a[8], b[4];
    #pragma unroll
    for (int mi = 0; mi < 8; ++mi)
      a[mi] = *(const bf16x8*)&A_s[cur][mi * 16 + c16][q * 8];
    #pragma unroll
    for (int nf = 0; nf < 4; ++nf) {
      const int col = n0 + nf * 16 + c16;
      b[nf] = *(const bf16x8*)&B_s[cur][col * BKS + ((q ^ ((col >> 1) & 3)) * 8)];
    }
    #pragma unroll
    for (int mi = 0; mi < 8; ++mi)
      #pragma unroll
      for (int nf = 0; nf < 4; ++nf)
        acc[mi][nf] = __builtin_amdgcn_mfma_f32_16x16x32_bf16(a[mi], b[nf], acc[mi][nf], 0, 0, 0);
    if (ks + 1 < NKS) WRITE_A(nxt, av);
    __syncthreads();
  }

  // ---- epilogue: rowsum += v[h] * tanh(acc + u[b][h]), reduce over h ----
  float rowsum[8][4];
  #pragma unroll
  for (int mi = 0; mi < 8; ++mi)
    #pragma unroll
    for (int r = 0; r < 4; ++r) rowsum[mi][r] = 0.f;

  #pragma unroll
  for (int nf = 0; nf < 4; ++nf) {
    const int h = n0 + nf * 16 + c16;
    const float vh = v[h];
    float uv[2][4];
    #pragma unroll
    for (int p = 0; p < 2; ++p)
      #pragma unroll
      for (int r = 0; r < 4; ++r)
        uv[p][r] = u[(size_t)(p * 16 + q * 4 + r) * H_DIM + h]; // b = row&31, row=(mi&1)*16+q*4+r
    #pragma unroll
    for (int mi = 0; mi < 8; ++mi)
      #pragma unroll
      for (int r = 0; r < 4; ++r) {
        float x = acc[mi][nf][r] + uv[mi & 1][r];
        rowsum[mi][r] += vh * fast_tanh(x);
      }
  }
  #pragma unroll
  for (int mi = 0; mi < 8; ++mi)
    #pragma unroll
    for (int r = 0; r < 4; ++r) {
      float s = rowsum[mi][r];
      s += __shfl_xor(s, 1);
      s += __shfl_xor(s, 2);
      s += __shfl_xor(s, 4);
      s += __shfl_xor(s, 8);
      if (c16 == 0) red_s[wid][mi * 16 + q * 4 + r] = s;
    }
  __syncthreads();
  if (tid < BM) {
    float s = 0.f;
    #pragma unroll
    for (int w = 0; w < 16; ++w) s += red_s[w][tid];
    scores[m0 + tid] = s;
  }
  #undef STAGE_B
  #undef WRITE_A
}

// softmax over S per batch row b; scores[m] with m = s*B + b; out[b][0][s]
__global__ void softmax_kernel(const float* __restrict__ scores, float* __restrict__ out) {
  const int b = blockIdx.x;
  const int t = threadIdx.x;        // 256
  const int lane = t & 63, wid = t >> 6;
  __shared__ float redm[4], reds[4];
  float loc[8];
  float mx = -3.0e38f;
  #pragma unroll
  for (int i = 0; i < 8; ++i) {
    loc[i] = scores[(size_t)(i * 256 + t) * B_DIM + b];
    mx = fmaxf(mx, loc[i]);
  }
  #pragma unroll
  for (int off = 1; off < 64; off <<= 1) mx = fmaxf(mx, __shfl_xor(mx, off));
  if (lane == 0) redm[wid] = mx;
  __syncthreads();
  mx = fmaxf(fmaxf(redm[0], redm[1]), fmaxf(redm[2], redm[3]));
  float sum = 0.f;
  #pragma unroll
  for (int i = 0; i < 8; ++i) { loc[i] = __expf(loc[i] - mx); sum += loc[i]; }
  #pragma unroll
  for (int off = 1; off < 64; off <<= 1) sum += __shfl_xor(sum, off);
  if (lane == 0) reds[wid] = sum;
  __syncthreads();
  sum = reds[0] + reds[1] + reds[2] + reds[3];
  float inv = 1.0f / sum;
  #pragma unroll
  for (int i = 0; i < 8; ++i) out[(size_t)b * S_DIM + i * 256 + t] = loc[i] * inv;
}

extern "C" void kernel_launch(void* const* d_in, const int* in_sizes, int n_in,
                              void* d_out, int out_size, void* d_ws, size_t ws_size,
                              hipStream_t stream) {
  const float* hidden = (const float*)d_in[0];
  const float* enc    = (const float*)d_in[1];
  const float* W      = (const float*)d_in[2];
  const float* bias   = (const float*)d_in[3];
  const float* v      = (const float*)d_in[4];
  float* out = (float*)d_out;

  char* ws = (char*)d_ws;
  u16*   W2     = (u16*)ws;                                        // 2 MB
  float* u      = (float*)(ws + (2u << 20));                       // 128 KB
  float* scores = (float*)(ws + (2u << 20) + (128u << 10));        // 256 KB

  wconv_kernel<<<H_DIM, 256, 0, stream>>>(W, W2);
  uprep_kernel<<<512, 256, 0, stream>>>(hidden, W, bias, u);
  gemm_kernel<<<M_DIM / BM, 1024, 0, stream>>>(enc, W2, u, v, scores);
  softmax_kernel<<<B_DIM, 256, 0, stream>>>(scores, out);
}

// Round 3
// 279.272 us; speedup vs baseline: 4.4995x; 4.4995x over previous
//
#include <hip/hip_runtime.h>
#include <hip/hip_bf16.h>

typedef unsigned short u16;
typedef unsigned long long u64;
typedef __bf16 bf16x8 __attribute__((ext_vector_type(8)));
typedef float f32x4 __attribute__((ext_vector_type(4)));

#define S_DIM 2048
#define B_DIM 32
#define H_DIM 1024
#define M_DIM (S_DIM * B_DIM)
#define BM 64
#define BKS 32
#define NKS (H_DIM / BKS)

__device__ __forceinline__ float fast_tanh(float x) {
  // tanh(x) = 1 - 2/(e^{2x}+1); e->inf => 1, e->0 => -1; no NaN
  float e = __expf(2.0f * x);
  return 1.0f - 2.0f * __builtin_amdgcn_rcpf(e + 1.0f);
}

__device__ __forceinline__ void gload_lds16(const void* g, void* l) {
  __builtin_amdgcn_global_load_lds(
      (const __attribute__((address_space(1))) unsigned int*)g,
      (__attribute__((address_space(3))) unsigned int*)l,
      16, 0, 0);
}

// Convert W_attn[:, H:2H] (f32, row stride 2H) -> W2 bf16 [H][H] row-major
__global__ void wconv_kernel(const float* __restrict__ W, u16* __restrict__ W2) {
  const int h = blockIdx.x;
  const int t = threadIdx.x; // 256 threads, 4 floats each
  float4 w4 = *(const float4*)(W + (size_t)h * (2 * H_DIM) + H_DIM + t * 4);
  union { u16 s[4]; uint2 v; } pk;
  pk.s[0] = __builtin_bit_cast(u16, (__bf16)w4.x);
  pk.s[1] = __builtin_bit_cast(u16, (__bf16)w4.y);
  pk.s[2] = __builtin_bit_cast(u16, (__bf16)w4.z);
  pk.s[3] = __builtin_bit_cast(u16, (__bf16)w4.w);
  *(uint2*)(W2 + (size_t)h * H_DIM + t * 4) = pk.v;
}

// u[b][h] = dot(hidden[b,:], W_attn[h, 0:H]) + b_attn[h]   (fp32)
__global__ void uprep_kernel(const float* __restrict__ hidden, const float* __restrict__ W,
                             const float* __restrict__ bias, float* __restrict__ u) {
  int t = blockIdx.x * 256 + threadIdx.x;   // 0..131071
  int h = t >> 7;
  int b = (t >> 2) & 31;
  int kq = t & 3;
  const float4* hv = (const float4*)(hidden + (size_t)b * H_DIM) + kq * 64;
  const float4* wv = (const float4*)(W + (size_t)h * (2 * H_DIM)) + kq * 64;
  float acc = 0.f;
  #pragma unroll 4
  for (int i = 0; i < 64; ++i) {
    float4 a = hv[i], w = wv[i];
    acc += a.x * w.x + a.y * w.y + a.z * w.z + a.w * w.w;
  }
  acc += __shfl_xor(acc, 1);
  acc += __shfl_xor(acc, 2);
  if (kq == 0) u[(size_t)b * H_DIM + h] = acc + bias[h];
}

// Fused GEMM + tanh + v-dot.
// Block: BM=64 rows x full N=1024. 512 threads = 8 waves; wave tile 64m x 128n
// (no cross-wave B duplication in LDS reads). acc[4][8] = 128 f32/thread.
// A (enc f32->bf16) reg-staged into padded LDS; B (W2 bf16) via global_load_lds,
// both double-buffered; both-sides XOR chunk swizzle on B (linear-dest rule).
__launch_bounds__(512, 2)
__global__ void gemm_kernel(const float* __restrict__ enc, const u16* __restrict__ W2,
                            const float* __restrict__ u, const float* __restrict__ v,
                            float* __restrict__ scores) {
  __shared__ u16 A_s[2][BM][40];        // 80B rows -> 2-way banks (free)
  __shared__ u16 B_s[2][H_DIM * BKS];   // [col][4 chunks of 8], chunk ^= (col>>1)&3
  __shared__ float red_s[8][BM];

  const int tid  = threadIdx.x;
  const int lane = tid & 63;
  const int wid  = tid >> 6;    // 0..7
  const int q    = lane >> 4;   // 0..3 (k-chunk)
  const int c16  = lane & 15;
  const int n0   = wid * 128;   // wave n-slice (128 cols)
  const int m0   = blockIdx.x * BM;

  // A staging coords: thread -> (row 0..63, 4-float chunk 0..7)
  const int ar  = tid >> 3;
  const int acf = tid & 7;
  const float* aptr = enc + (size_t)(m0 + ar) * H_DIM + acf * 4;

  f32x4 acc[4][8];
  #pragma unroll
  for (int mi = 0; mi < 4; ++mi)
    #pragma unroll
    for (int nf = 0; nf < 8; ++nf) {
      f32x4 z = {0.f, 0.f, 0.f, 0.f};
      acc[mi][nf] = z;
    }

  // B staging: 64KB = 4096 x 16B slots; 512 thr x 8 slots. Slot L16 holds
  // col=L16>>2, chunk cp=L16&3, sourced from global chunk cp ^ ((col>>1)&3).
  #define STAGE_B(buf, ks)                                                     \
    {                                                                          \
      _Pragma("unroll")                                                        \
      for (int j = 0; j < 8; ++j) {                                            \
        const int L16 = j * 512 + tid;                                         \
        const int h   = L16 >> 2;                                              \
        const int cp  = L16 & 3;                                               \
        const int c   = cp ^ ((h >> 1) & 3);                                   \
        gload_lds16(W2 + (size_t)h * H_DIM + (ks) * BKS + c * 8,               \
                    &B_s[buf][L16 * 8]);                                       \
      }                                                                        \
    }

  #define WRITE_A(buf, f4)                                                     \
    {                                                                          \
      union { u16 s[4]; u64 v; } pk;                                           \
      pk.s[0] = __builtin_bit_cast(u16, (__bf16)(f4).x);                       \
      pk.s[1] = __builtin_bit_cast(u16, (__bf16)(f4).y);                       \
      pk.s[2] = __builtin_bit_cast(u16, (__bf16)(f4).z);                       \
      pk.s[3] = __builtin_bit_cast(u16, (__bf16)(f4).w);                       \
      *(u64*)&A_s[buf][ar][acf * 4] = pk.v;                                    \
    }

  // ---- prologue ----
  STAGE_B(0, 0);
  {
    float4 a0 = *(const float4*)(aptr);
    WRITE_A(0, a0);
  }
  __syncthreads();

  // ---- K loop ----
  #pragma unroll 2
  for (int ks = 0; ks < NKS; ++ks) {
    const int cur = ks & 1;
    const int nxt = cur ^ 1;
    float4 av;
    if (ks + 1 < NKS) {
      STAGE_B(nxt, ks + 1);
      av = *(const float4*)(aptr + (ks + 1) * BKS);
    }
    bf16x8 a[4], b[8];
    #pragma unroll
    for (int mi = 0; mi < 4; ++mi)
      a[mi] = *(const bf16x8*)&A_s[cur][mi * 16 + c16][q * 8];
    #pragma unroll
    for (int nf = 0; nf < 8; ++nf) {
      const int col = n0 + nf * 16 + c16;
      b[nf] = *(const bf16x8*)&B_s[cur][col * BKS + ((q ^ ((col >> 1) & 3)) * 8)];
    }
    #pragma unroll
    for (int nf = 0; nf < 8; ++nf)
      #pragma unroll
      for (int mi = 0; mi < 4; ++mi)
        acc[mi][nf] = __builtin_amdgcn_mfma_f32_16x16x32_bf16(a[mi], b[nf], acc[mi][nf], 0, 0, 0);
    if (ks + 1 < NKS) WRITE_A(nxt, av);
    __syncthreads();
  }

  // ---- epilogue: rowsum += v[h] * tanh(acc + u[b][h]), reduce over h ----
  float rowsum[4][4];
  #pragma unroll
  for (int mi = 0; mi < 4; ++mi)
    #pragma unroll
    for (int r = 0; r < 4; ++r) rowsum[mi][r] = 0.f;

  #pragma unroll
  for (int nf = 0; nf < 8; ++nf) {
    const int h = n0 + nf * 16 + c16;
    const float vh = v[h];
    float uv[2][4];
    #pragma unroll
    for (int p = 0; p < 2; ++p)
      #pragma unroll
      for (int r = 0; r < 4; ++r)
        uv[p][r] = u[(size_t)(p * 16 + q * 4 + r) * H_DIM + h]; // b=(row)&31, row=(mi&1)*16+q*4+r
    #pragma unroll
    for (int mi = 0; mi < 4; ++mi)
      #pragma unroll
      for (int r = 0; r < 4; ++r) {
        float x = acc[mi][nf][r] + uv[mi & 1][r];
        rowsum[mi][r] += vh * fast_tanh(x);
      }
  }
  #pragma unroll
  for (int mi = 0; mi < 4; ++mi)
    #pragma unroll
    for (int r = 0; r < 4; ++r) {
      float s = rowsum[mi][r];
      s += __shfl_xor(s, 1);
      s += __shfl_xor(s, 2);
      s += __shfl_xor(s, 4);
      s += __shfl_xor(s, 8);
      if (c16 == 0) red_s[wid][mi * 16 + q * 4 + r] = s;
    }
  __syncthreads();
  if (tid < BM) {
    float s = 0.f;
    #pragma unroll
    for (int w = 0; w < 8; ++w) s += red_s[w][tid];
    scores[m0 + tid] = s;
  }
  #undef STAGE_B
  #undef WRITE_A
}

// softmax over S per batch row b; scores[m] with m = s*B + b; out[b][0][s]
__global__ void softmax_kernel(const float* __restrict__ scores, float* __restrict__ out) {
  const int b = blockIdx.x;
  const int t = threadIdx.x;        // 256
  const int lane = t & 63, wid = t >> 6;
  __shared__ float redm[4], reds[4];
  float loc[8];
  float mx = -3.0e38f;
  #pragma unroll
  for (int i = 0; i < 8; ++i) {
    loc[i] = scores[(size_t)(i * 256 + t) * B_DIM + b];
    mx = fmaxf(mx, loc[i]);
  }
  #pragma unroll
  for (int off = 1; off < 64; off <<= 1) mx = fmaxf(mx, __shfl_xor(mx, off));
  if (lane == 0) redm[wid] = mx;
  __syncthreads();
  mx = fmaxf(fmaxf(redm[0], redm[1]), fmaxf(redm[2], redm[3]));
  float sum = 0.f;
  #pragma unroll
  for (int i = 0; i < 8; ++i) { loc[i] = __expf(loc[i] - mx); sum += loc[i]; }
  #pragma unroll
  for (int off = 1; off < 64; off <<= 1) sum += __shfl_xor(sum, off);
  if (lane == 0) reds[wid] = sum;
  __syncthreads();
  sum = reds[0] + reds[1] + reds[2] + reds[3];
  float inv = 1.0f / sum;
  #pragma unroll
  for (int i = 0; i < 8; ++i) out[(size_t)b * S_DIM + i * 256 + t] = loc[i] * inv;
}

extern "C" void kernel_launch(void* const* d_in, const int* in_sizes, int n_in,
                              void* d_out, int out_size, void* d_ws, size_t ws_size,
                              hipStream_t stream) {
  const float* hidden = (const float*)d_in[0];
  const float* enc    = (const float*)d_in[1];
  const float* W      = (const float*)d_in[2];
  const float* bias   = (const float*)d_in[3];
  const float* v      = (const float*)d_in[4];
  float* out = (float*)d_out;

  char* ws = (char*)d_ws;
  u16*   W2     = (u16*)ws;                                        // 2 MB
  float* u      = (float*)(ws + (2u << 20));                       // 128 KB
  float* scores = (float*)(ws + (2u << 20) + (128u << 10));        // 256 KB

  wconv_kernel<<<H_DIM, 256, 0, stream>>>(W, W2);
  uprep_kernel<<<512, 256, 0, stream>>>(hidden, W, bias, u);
  gemm_kernel<<<M_DIM / BM, 512, 0, stream>>>(enc, W2, u, v, scores);
  softmax_kernel<<<B_DIM, 256, 0, stream>>>(scores, out);
}